// Round 18
// baseline (276.923 us; speedup 1.0000x reference)
//
#include <hip/hip_runtime.h>

#define NPTS 8192
#define BATCH 2

typedef __attribute__((ext_vector_type(8))) __bf16 bf16x8;
typedef __attribute__((ext_vector_type(4))) float f32x4;
typedef unsigned int u32;

// ---------------- helpers ----------------
__device__ inline unsigned short f2bf(float x) {   // fp32 -> bf16 RNE
    unsigned u = __float_as_uint(x);
    u += 0x7fffu + ((u >> 16) & 1u);
    return (unsigned short)(u >> 16);
}
// 32-bit knn key: orderable(d) high 19 bits | 13-bit index
__device__ inline unsigned pack32(float d, unsigned idx) {
    unsigned u = __float_as_uint(d);
    u ^= ((unsigned)((int)u >> 31)) | 0x80000000u;
    return (u & 0xFFFFE000u) | idx;
}
// full-wave bitonic sort (64 u32 keys ascending by lane)
__device__ inline unsigned bitonic64u(unsigned key, int lane) {
#pragma unroll
    for (int k = 2; k <= 64; k <<= 1) {
#pragma unroll
        for (int j = k >> 1; j > 0; j >>= 1) {
            unsigned o = __shfl_xor(key, j, 64);
            bool tmin = (((lane & k) == 0) == ((lane & j) == 0));
            key = ((o < key) == tmin) ? o : key;
        }
    }
    return key;
}
// sorted-insert of wave-uniform candidate c (ascending list across lanes)
__device__ inline void ins16(unsigned& key, unsigned c, int lane) {
    unsigned prev = __shfl_up(key, 1, 64);
    if (lane == 0) prev = 0u;
    unsigned mx = prev > c ? prev : c;
    key = mx < key ? mx : key;
}
__device__ inline float distf(float4 q, float4 p) {
    return fmaf(-2.f, fmaf(q.z, p.z, fmaf(q.y, p.y, q.x * p.x)), q.w + p.w);
}

// ---------------- prep (blocks 0..63) + weight presplit (blocks 64..2271) ----------------
__global__ __launch_bounds__(256) void prep_presplit(
    const float* __restrict__ pc, float* __restrict__ oxyz, float4* __restrict__ pq,
    const float* __restrict__ W0, const float* __restrict__ W1,
    const float* __restrict__ W2, const float* __restrict__ W3,
    const float* __restrict__ W4, const float* __restrict__ W5,
    unsigned short* __restrict__ wsp) {
    int bx = blockIdx.x, tid = threadIdx.x;
    if (bx < 64) {
        int t = bx * 256 + tid;
        float x = pc[t * 3 + 0], y = pc[t * 3 + 1], z = pc[t * 3 + 2];
        oxyz[t * 3 + 0] = x; oxyz[t * 3 + 1] = y; oxyz[t * 3 + 2] = z;
        pq[t] = make_float4(x, y, z, fmaf(z, z, fmaf(y, y, x * x)));
        return;
    }
    int pb = bx - 64;
    const float* W; int O, C, OP; size_t off; int base;
    if (pb < 1024)      { W = W0; O = 256; C = 1024; OP = 256; off = 0;       base = 0; }
    else if (pb < 1152) { W = W1; O =  64; C =  256; OP = 128; off = 524288;  base = 1024; }
    else if (pb < 1184) { W = W2; O =  32; C =   64; OP = 128; off = 589824;  base = 1152; }
    else if (pb < 1568) { W = W3; O = 512; C =  164; OP = 512; off = 606208;  base = 1184; }
    else if (pb < 2080) { W = W4; O = 256; C =  512; OP = 256; off = 802816;  base = 1568; }
    else                { W = W5; O = 128; C =  256; OP = 128; off = 1064960; base = 2080; }
    unsigned short* dst = wsp + off;
    int t = (pb - base) * 256 + tid;
    int kk = t & 31;
    int o = (t >> 5) % OP;
    int kt = t / (OP * 32);
    int c = kt * 32 + kk;
    float x = (o < O && c < C) ? W[o * C + c] : 0.f;
    unsigned short hb = f2bf(x);
    float hf = __uint_as_float((unsigned)hb << 16);
    unsigned short lb = f2bf(x - hf);
    int s = kk >> 3, pos = kk & 7;
    int sst = s ^ ((o >> 1) & 3);            // pre-swizzle for conflict-free read
    dst[((size_t)(kt * 2) * OP + o) * 32 + sst * 8 + pos] = hb;
    dst[((size_t)(kt * 2 + 1) * OP + o) * 32 + sst * 8 + pos] = lb;
}

// ---------------- split-bf16 MFMA GEMM: BO=64 tile, 4 waves 2x2 (wave 32x32) ----------------
// Block tile 64(o) x 64(n), BK=32. W LDS: linear [64][64B] (slot-swizzled).
// X LDS: [64][80B]. X kt+1 reg-prefetched. Reads ready stats, writes partials.
template <int MODE>
__global__ __launch_bounds__(256, 4) void mfma_gemm(
    const unsigned short* __restrict__ Wsp, const float* __restrict__ bias,
    const float* __restrict__ X, float* __restrict__ out,
    int O, int C, int OP, int nK,
    const float2* __restrict__ stats,
    const float* __restrict__ h1, const float* __restrict__ h3,
    const float2* __restrict__ stats3,
    float2* __restrict__ partout) {
    const int N = NPTS;
    int tid = threadIdx.x;
    int lane = tid & 63, w = tid >> 6;
    int wm = w >> 1, wn = w & 1;
    int b = blockIdx.z, n0 = blockIdx.x * 64, o0 = blockIdx.y * 64;
    int nblk = blockIdx.x;
    int n = n0 + lane;

    __shared__ __align__(16) unsigned char lds[18432];
    __shared__ float ps1[2][64], ps2[2][64];
    unsigned char* WHp = lds;            // [64][64B] linear (swizzled slots)
    unsigned char* WLp = lds + 4096;
    unsigned char* XHp = lds + 8192;     // [64][80B]
    unsigned char* XLp = lds + 13312;

    f32x4 acc[2][2];
#pragma unroll
    for (int i = 0; i < 2; ++i)
#pragma unroll
        for (int j = 0; j < 2; ++j) acc[i][j] = (f32x4){0.f, 0.f, 0.f, 0.f};

    float xcur[8], xnxt[8];
    auto loadx = [&](int kt, float (&dst)[8]) {
#pragma unroll
        for (int i = 0; i < 8; ++i) {
            int c = kt * 32 + w * 8 + i;
            float x = 0.f;
            if (MODE == 0 || MODE == 1) {
                if (c < C) x = X[((size_t)(b * C + c)) * N + n];
            } else {
                if (c < 128)       x = h1[((size_t)(b * 128 + c)) * N + n];
                else if (c < 160)  x = X[((size_t)(b * 32 + (c - 128))) * N + n];
                else if (c < 164)  x = h3[((size_t)(b * 4 + (c - 160))) * N + n];
            }
            dst[i] = x;
        }
    };

    loadx(0, xcur);
    for (int kt = 0; kt < nK; ++kt) {
        int c0 = kt * 32;
        // ---- async W staging direct to LDS: 2 comps x 4 chunks of 1KB ----
#pragma unroll
        for (int comp = 0; comp < 2; ++comp) {
            const unsigned short* gb = Wsp + ((size_t)(kt * 2 + comp) * OP + o0) * 32;
            unsigned char* lb = comp ? WLp : WHp;
            __builtin_amdgcn_global_load_lds(
                (const __attribute__((address_space(1))) u32*)(gb + w * 512 + lane * 8),
                (__attribute__((address_space(3))) u32*)(lb + w * 1024),
                16, 0, 0);
        }
        // ---- transform + split current X tile into LDS ----
        {
            union { bf16x8 s; unsigned short u[8]; } hh, ll;
#pragma unroll
            for (int i = 0; i < 8; ++i) {
                int c = c0 + w * 8 + i;
                float x = xcur[i];
                if (MODE == 1) {
                    if (c < C) {
                        float2 st = stats[c];
                        x = fmaxf(fmaf(x, st.x, st.y), 0.f);
                    }
                } else if (MODE == 2) {
                    if (c >= 128 && c < 160) {
                        float2 st = stats3[c - 128];
                        x = fmaxf(fmaf(x, st.x, st.y), 0.f);
                    }
                }
                unsigned short hb = f2bf(x);
                float hf = __uint_as_float((unsigned)hb << 16);
                unsigned short lb = f2bf(x - hf);
                hh.u[i] = hb; ll.u[i] = lb;
            }
            *(bf16x8*)(XHp + lane * 80 + w * 16) = hh.s;
            *(bf16x8*)(XLp + lane * 80 + w * 16) = ll.s;
        }
        if (kt + 1 < nK) loadx(kt + 1, xnxt);   // loads fly during MFMA below
        __syncthreads();
        // ---- fragments + MFMA: wave tile 32(o) x 32(n), 12 MFMA ----
        {
            int koff = (lane >> 4) * 16;
            bf16x8 bh[2], bl[2];
#pragma unroll
            for (int ni = 0; ni < 2; ++ni) {
                int rb = wn * 32 + ni * 16 + (lane & 15);
                bh[ni] = *(const bf16x8*)(XHp + rb * 80 + koff);
                bl[ni] = *(const bf16x8*)(XLp + rb * 80 + koff);
            }
#pragma unroll
            for (int mi = 0; mi < 2; ++mi) {
                int ra = wm * 32 + mi * 16 + (lane & 15);
                int sw = koff ^ ((((unsigned)ra >> 1) & 3) * 16);   // un-swizzle
                bf16x8 ah = *(const bf16x8*)(WHp + ra * 64 + sw);
                bf16x8 al = *(const bf16x8*)(WLp + ra * 64 + sw);
#pragma unroll
                for (int ni = 0; ni < 2; ++ni) {
                    acc[mi][ni] = __builtin_amdgcn_mfma_f32_16x16x32_bf16(ah, bh[ni], acc[mi][ni], 0, 0, 0);
                    acc[mi][ni] = __builtin_amdgcn_mfma_f32_16x16x32_bf16(ah, bl[ni], acc[mi][ni], 0, 0, 0);
                    acc[mi][ni] = __builtin_amdgcn_mfma_f32_16x16x32_bf16(al, bh[ni], acc[mi][ni], 0, 0, 0);
                }
            }
        }
        __syncthreads();
        if (kt + 1 < nK) {
#pragma unroll
            for (int i = 0; i < 8; ++i) xcur[i] = xnxt[i];
        }
    }
    // ---- epilogue: write out + per-block partial stats (bias included) ----
    int col = lane & 15, rq = lane >> 4;
#pragma unroll
    for (int mi = 0; mi < 2; ++mi) {
#pragma unroll
        for (int j = 0; j < 4; ++j) {
            int oloc = wm * 32 + mi * 16 + rq * 4 + j;
            int o = o0 + oloc;
            float s1 = 0.f, s2 = 0.f;
            if (o < O) {
                float bs = bias[o];
                float v0 = acc[mi][0][j] + bs;
                float v1 = acc[mi][1][j] + bs;
                float* po = out + ((size_t)(b * O + o)) * N + n0 + wn * 32 + col;
                po[0] = v0; po[16] = v1;
                s1 = v0 + v1;
                s2 = fmaf(v0, v0, v1 * v1);
            }
#pragma unroll
            for (int mm = 1; mm < 16; mm <<= 1) {
                s1 += __shfl_xor(s1, mm, 64);
                s2 += __shfl_xor(s2, mm, 64);
            }
            if (col == 0) { ps1[wn][oloc] = s1; ps2[wn][oloc] = s2; }
        }
    }
    __syncthreads();
    if (tid < 64) {
        int o = o0 + tid;
        if (o < O)
            partout[(size_t)o * 256 + b * 128 + nblk] =
                make_float2(ps1[0][tid] + ps1[1][tid], ps2[0][tid] + ps2[1][tid]);
    }
}

// ---------------- finalize stats from partials: one block per channel ----------------
__global__ __launch_bounds__(256) void finalize_kernel(const float2* __restrict__ part,
                                                       const float* __restrict__ g,
                                                       const float* __restrict__ be,
                                                       float2* __restrict__ st) {
    int c = blockIdx.x;
    int tid = threadIdx.x;
    __shared__ float r1[256], r2[256];
    float2 v = part[(size_t)c * 256 + tid];
    r1[tid] = v.x; r2[tid] = v.y;
    __syncthreads();
    for (int off = 128; off > 0; off >>= 1) {
        if (tid < off) { r1[tid] += r1[tid + off]; r2[tid] += r2[tid + off]; }
        __syncthreads();
    }
    if (tid == 0) {
        const float inv = 1.f / (BATCH * NPTS);
        float m = r1[0] * inv;
        float var = r2[0] * inv - m * m;
        float sc = g[c] * rsqrtf(var + 1e-5f);
        st[c] = make_float2(sc, be[c] - m * sc);
    }
}

// ---------------- C3 stats (from partials) + bn_relu into d_out ----------------
__global__ __launch_bounds__(256) void stats_final_kernel(
    const float2* __restrict__ part, const float* __restrict__ g,
    const float* __restrict__ be, const float* __restrict__ X,
    float* __restrict__ outz) {
    const int N = NPTS;
    const int C = 128;
    int c = blockIdx.x;
    int tid = threadIdx.x;
    __shared__ float r1[256], r2[256];
    __shared__ float2 stv;
    float2 v = part[(size_t)c * 256 + tid];
    r1[tid] = v.x; r2[tid] = v.y;
    __syncthreads();
    for (int off = 128; off > 0; off >>= 1) {
        if (tid < off) { r1[tid] += r1[tid + off]; r2[tid] += r2[tid + off]; }
        __syncthreads();
    }
    if (tid == 0) {
        const float inv = 1.f / (BATCH * NPTS);
        float m = r1[0] * inv;
        float var = r2[0] * inv - m * m;
        float sc = g[c] * rsqrtf(var + 1e-5f);
        stv = make_float2(sc, be[c] - m * sc);
    }
    __syncthreads();
    float2 s = stv;
    for (int b = 0; b < BATCH; ++b) {
        const float* p = X + (size_t)(b * C + c) * N;
        float* q = outz + (size_t)(b * C + c) * N;
        for (int nn = tid * 4; nn < N; nn += 1024) {
            float4 v4 = *(const float4*)(p + nn);
            v4.x = fmaxf(fmaf(v4.x, s.x, s.y), 0.f);
            v4.y = fmaxf(fmaf(v4.y, s.x, s.y), 0.f);
            v4.z = fmaxf(fmaf(v4.z, s.x, s.y), 0.f);
            v4.w = fmaxf(fmaf(v4.w, s.x, s.y), 0.f);
            *(float4*)(q + nn) = v4;
        }
    }
}

// ---------------- KNN(16) v6: 2 queries/wave, 2-tile pipelined scan ----------------
__global__ __launch_bounds__(256) void knn_eig_kernel(
    const float4* __restrict__ pq,
    const float* __restrict__ ew1, const float* __restrict__ eb1,
    const float* __restrict__ ew2, const float* __restrict__ eb2,
    float* __restrict__ h3) {
    int wv = threadIdx.x >> 6;
    int lane = threadIdx.x & 63;
    int sg = blockIdx.x * 4 + wv;          // query-pair id, 0..8191
    int b = sg >> 12;
    int iloc = (sg & 4095) << 1;
    const float4* pqb = pq + (size_t)b * NPTS;
    float4 Q0 = pqb[iloc + 0], Q1 = pqb[iloc + 1];

    float4 p = pqb[lane];
    unsigned k0 = bitonic64u(pack32(distf(Q0, p), lane), lane);
    unsigned k1 = bitonic64u(pack32(distf(Q1, p), lane), lane);
    unsigned tk0 = (unsigned)__builtin_amdgcn_readlane((int)k0, 15);
    unsigned tk1 = (unsigned)__builtin_amdgcn_readlane((int)k1, 15);

    float4 A = pqb[64 + lane];
    float4 B = pqb[128 + lane];
    for (int it = 1; it + 1 < 128; it += 2) {
        int tbA = it * 64, tbB = tbA + 64;
        int t3 = (it + 3 < 128) ? it + 3 : 0;
        float4 Cx = pqb[(it + 2) * 64 + lane];
        float4 Dx = pqb[t3 * 64 + lane];
        unsigned cA0 = pack32(distf(Q0, A), tbA + lane);
        unsigned cA1 = pack32(distf(Q1, A), tbA + lane);
        unsigned cB0 = pack32(distf(Q0, B), tbB + lane);
        unsigned cB1 = pack32(distf(Q1, B), tbB + lane);
        unsigned long long mA0 = __ballot(cA0 < tk0), mB0 = __ballot(cB0 < tk0);
        unsigned long long mA1 = __ballot(cA1 < tk1), mB1 = __ballot(cB1 < tk1);
        if (mA0 | mA1 | mB0 | mB1) {
            while (mA0) {
                int L = __ffsll((long long)mA0) - 1; mA0 &= mA0 - 1;
                ins16(k0, (unsigned)__builtin_amdgcn_readlane((int)cA0, L), lane);
            }
            while (mB0) {
                int L = __ffsll((long long)mB0) - 1; mB0 &= mB0 - 1;
                ins16(k0, (unsigned)__builtin_amdgcn_readlane((int)cB0, L), lane);
            }
            while (mA1) {
                int L = __ffsll((long long)mA1) - 1; mA1 &= mA1 - 1;
                ins16(k1, (unsigned)__builtin_amdgcn_readlane((int)cA1, L), lane);
            }
            while (mB1) {
                int L = __ffsll((long long)mB1) - 1; mB1 &= mB1 - 1;
                ins16(k1, (unsigned)__builtin_amdgcn_readlane((int)cB1, L), lane);
            }
            tk0 = (unsigned)__builtin_amdgcn_readlane((int)k0, 15);
            tk1 = (unsigned)__builtin_amdgcn_readlane((int)k1, 15);
        }
        A = Cx; B = Dx;
    }
    // tail tile 127 (in A)
    {
        int tbA = 127 * 64;
        unsigned cA0 = pack32(distf(Q0, A), tbA + lane);
        unsigned cA1 = pack32(distf(Q1, A), tbA + lane);
        unsigned long long mA0 = __ballot(cA0 < tk0);
        unsigned long long mA1 = __ballot(cA1 < tk1);
        while (mA0) {
            int L = __ffsll((long long)mA0) - 1; mA0 &= mA0 - 1;
            ins16(k0, (unsigned)__builtin_amdgcn_readlane((int)cA0, L), lane);
        }
        while (mA1) {
            int L = __ffsll((long long)mA1) - 1; mA1 &= mA1 - 1;
            ins16(k1, (unsigned)__builtin_amdgcn_readlane((int)cA1, L), lane);
        }
    }

    int g = lane >> 4, r = lane & 15;
    unsigned j0 = ((unsigned)__shfl((int)k0, r, 64)) & 8191u;
    unsigned j1 = ((unsigned)__shfl((int)k1, r, 64)) & 8191u;
    unsigned nj = ((g & 1) == 0) ? j0 : j1;

    float4 nb = pqb[nj];
    float sx = nb.x, sy = nb.y, sz = nb.z;
#pragma unroll
    for (int m = 1; m < 16; m <<= 1) {
        sx += __shfl_xor(sx, m, 64);
        sy += __shfl_xor(sy, m, 64);
        sz += __shfl_xor(sz, m, 64);
    }
    const float i16 = 1.f / 16.f;
    float cx = nb.x - sx * i16, cy = nb.y - sy * i16, cz = nb.z - sz * i16;
    float xx = cx * cx, xy = cx * cy, xz = cx * cz, yy = cy * cy, yz = cy * cz, zz = cz * cz;
#pragma unroll
    for (int m = 1; m < 16; m <<= 1) {
        xx += __shfl_xor(xx, m, 64); xy += __shfl_xor(xy, m, 64); xz += __shfl_xor(xz, m, 64);
        yy += __shfl_xor(yy, m, 64); yz += __shfl_xor(yz, m, 64); zz += __shfl_xor(zz, m, 64);
    }
    float a11 = xx * i16, a12 = xy * i16, a13 = xz * i16,
          a22 = yy * i16, a23 = yz * i16, a33 = zz * i16;
    float q = (a11 + a22 + a33) * (1.f / 3.f);
    float p1 = a12 * a12 + a13 * a13 + a23 * a23;
    float b11 = a11 - q, b22 = a22 - q, b33 = a33 - q;
    float p2 = b11 * b11 + b22 * b22 + b33 * b33 + 2.f * p1;
    float pr = sqrtf(p2 * (1.f / 6.f));
    float ipv = (p2 > 1e-32f) ? (1.f / pr) : 0.f;
    float detB = b11 * (b22 * b33 - a23 * a23) - a12 * (a12 * b33 - a23 * a13) +
                 a13 * (a12 * a23 - b22 * a13);
    float r3 = 0.5f * detB * ipv * ipv * ipv;
    r3 = fminf(1.f, fmaxf(-1.f, r3));
    float phi = acosf(r3) * (1.f / 3.f);
    float e1 = q + 2.f * pr * cosf(phi);
    float e3 = q + 2.f * pr * cosf(phi + 2.0943951023931953f);
    float e2 = 3.f * q - e1 - e3;
    float ev0 = e3, ev1 = e2, ev2 = e1;
    float h[4], o[4];
#pragma unroll
    for (int kk = 0; kk < 4; ++kk)
        h[kk] = fmaxf(eb1[kk] + ev0 * ew1[kk] + ev1 * ew1[4 + kk] + ev2 * ew1[8 + kk], 0.f);
#pragma unroll
    for (int kk = 0; kk < 4; ++kk)
        o[kk] = eb2[kk] + h[0] * ew2[kk] + h[1] * ew2[4 + kk] + h[2] * ew2[8 + kk] +
                h[3] * ew2[12 + kk];
    int ipt = iloc + (g & 1);
    if (r == 0 && g < 2) {
#pragma unroll
        for (int kk = 0; kk < 4; ++kk) h3[(b * 4 + kk) * NPTS + ipt] = o[kk];
    }
}

// ---------------- launch ----------------
extern "C" void kernel_launch(void* const* d_in, const int* in_sizes, int n_in,
                              void* d_out, int out_size, void* d_ws, size_t ws_size,
                              hipStream_t stream) {
    const float* pc    = (const float*)d_in[0];
    const float* h1    = (const float*)d_in[1];
    const float* h2    = (const float*)d_in[2];
    const float* DG_w1 = (const float*)d_in[4];
    const float* DG_b1 = (const float*)d_in[5];
    const float* DG_g1 = (const float*)d_in[6];
    const float* DG_be1= (const float*)d_in[7];
    const float* DG_w2 = (const float*)d_in[8];
    const float* DG_b2 = (const float*)d_in[9];
    const float* DG_g2 = (const float*)d_in[10];
    const float* DG_be2= (const float*)d_in[11];
    const float* DG_w3 = (const float*)d_in[12];
    const float* DG_b3 = (const float*)d_in[13];
    const float* DG_g3 = (const float*)d_in[14];
    const float* DG_be3= (const float*)d_in[15];
    const float* ED_w1 = (const float*)d_in[16];
    const float* ED_b1 = (const float*)d_in[17];
    const float* ED_w2 = (const float*)d_in[18];
    const float* ED_b2 = (const float*)d_in[19];
    const float* C_w1  = (const float*)d_in[20];
    const float* C_b1  = (const float*)d_in[21];
    const float* C_g1  = (const float*)d_in[22];
    const float* C_be1 = (const float*)d_in[23];
    const float* C_w2  = (const float*)d_in[24];
    const float* C_b2  = (const float*)d_in[25];
    const float* C_g2  = (const float*)d_in[26];
    const float* C_be2 = (const float*)d_in[27];
    const float* C_w3  = (const float*)d_in[28];
    const float* C_b3  = (const float*)d_in[29];
    const float* C_g3  = (const float*)d_in[30];
    const float* C_be3 = (const float*)d_in[31];

    float* ws = (float*)d_ws;
    float* A  = ws;                       // DG1-out then C1-out
    float* Bb = ws + (8l << 20);          // DG2-out then C2-out
    float* Cc = ws + (12l << 20);         // DG3-out then C3-out
    float* H3 = ws + (14l << 20);         // 65536 floats
    float4* PQ = (float4*)(H3 + 65536);   // 16384 float4
    float2* ST = (float2*)(H3 + 131072);  // finalized stats
    unsigned short* WSP = (unsigned short*)(H3 + 131072 + 2560);

    // partial-stats buffers in liveness-safe slack:
    float2* P_DG1 = (float2*)(Bb + (1l << 20));                       // 65536 f2 (dead before C2 writes Bb)
    float2* P_DG2 = (float2*)(Bb + (1l << 20) + 131072);              // 16384 f2
    float2* P_DG3 = (float2*)(Bb + (1l << 20) + 131072 + 32768);      //  8192 f2
    float2* P_C1  = (float2*)(Cc + (1l << 20));                       // 131072 f2 (dead before C3 writes Cc)
    float2* TAIL  = (float2*)(WSP + 1130496);
    float2* P_C2  = TAIL;                                             // 65536 f2
    float2* P_C3  = TAIL + 65536;                                     // 32768 f2

    const size_t W1SP = 0;
    const size_t W2SP = 524288;
    const size_t W3SP = 589824;
    const size_t C1SP = 606208;
    const size_t C2SP = 802816;
    const size_t C3SP = 1064960;

    float* outxyz = (float*)d_out;
    float* outz   = (float*)d_out + BATCH * NPTS * 3;

    prep_presplit<<<2272, 256, 0, stream>>>(pc, outxyz, PQ,
                                            DG_w1, DG_w2, DG_w3, C_w1, C_w2, C_w3, WSP);

    // DG stack (partials -> tiny finalize -> consumer reads ready ST)
    mfma_gemm<0><<<dim3(128, 4, 2), 256, 0, stream>>>(WSP + W1SP, DG_b1, h2, A, 256, 1024, 256, 32,
                                                      nullptr, nullptr, nullptr, nullptr, P_DG1);
    finalize_kernel<<<256, 256, 0, stream>>>(P_DG1, DG_g1, DG_be1, ST + 0);
    mfma_gemm<1><<<dim3(128, 1, 2), 256, 0, stream>>>(WSP + W2SP, DG_b2, A, Bb, 64, 256, 128, 8,
                                                      ST + 0, nullptr, nullptr, nullptr, P_DG2);
    finalize_kernel<<<64, 256, 0, stream>>>(P_DG2, DG_g2, DG_be2, ST + 256);
    mfma_gemm<1><<<dim3(128, 1, 2), 256, 0, stream>>>(WSP + W3SP, DG_b3, Bb, Cc, 32, 64, 128, 2,
                                                      ST + 256, nullptr, nullptr, nullptr, P_DG3);
    finalize_kernel<<<32, 256, 0, stream>>>(P_DG3, DG_g3, DG_be3, ST + 320);

    // KNN + eig + ED MLP
    knn_eig_kernel<<<2048, 256, 0, stream>>>(PQ, ED_w1, ED_b1, ED_w2, ED_b2, H3);

    // C stack
    mfma_gemm<2><<<dim3(128, 8, 2), 256, 0, stream>>>(WSP + C1SP, C_b1, Cc, A, 512, 164, 512, 6,
                                                      nullptr, h1, H3, ST + 320, P_C1);
    finalize_kernel<<<512, 256, 0, stream>>>(P_C1, C_g1, C_be1, ST + 352);
    mfma_gemm<1><<<dim3(128, 4, 2), 256, 0, stream>>>(WSP + C2SP, C_b2, A, Bb, 256, 512, 256, 16,
                                                      ST + 352, nullptr, nullptr, nullptr, P_C2);
    finalize_kernel<<<256, 256, 0, stream>>>(P_C2, C_g2, C_be2, ST + 864);
    mfma_gemm<1><<<dim3(128, 2, 2), 256, 0, stream>>>(WSP + C3SP, C_b3, Bb, Cc, 128, 256, 128, 8,
                                                      ST + 864, nullptr, nullptr, nullptr, P_C3);

    // C3 stats (from partials) + bn_relu, writes final output
    stats_final_kernel<<<128, 256, 0, stream>>>(P_C3, C_g3, C_be3, Cc, outz);
}

// Round 19
// 263.347 us; speedup vs baseline: 1.0515x; 1.0515x over previous
//
#include <hip/hip_runtime.h>

#define NPTS 8192
#define BATCH 2

typedef __attribute__((ext_vector_type(8))) __bf16 bf16x8;
typedef __attribute__((ext_vector_type(4))) float f32x4;
typedef unsigned int u32;

// ---------------- helpers ----------------
__device__ inline unsigned short f2bf(float x) {   // fp32 -> bf16 RNE
    unsigned u = __float_as_uint(x);
    u += 0x7fffu + ((u >> 16) & 1u);
    return (unsigned short)(u >> 16);
}
__device__ inline unsigned pack32(float d, unsigned idx) {
    unsigned u = __float_as_uint(d);
    u ^= ((unsigned)((int)u >> 31)) | 0x80000000u;
    return (u & 0xFFFFE000u) | idx;
}
__device__ inline unsigned bitonic64u(unsigned key, int lane) {
#pragma unroll
    for (int k = 2; k <= 64; k <<= 1) {
#pragma unroll
        for (int j = k >> 1; j > 0; j >>= 1) {
            unsigned o = __shfl_xor(key, j, 64);
            bool tmin = (((lane & k) == 0) == ((lane & j) == 0));
            key = ((o < key) == tmin) ? o : key;
        }
    }
    return key;
}
__device__ inline void ins16(unsigned& key, unsigned c, int lane) {
    unsigned prev = __shfl_up(key, 1, 64);
    if (lane == 0) prev = 0u;
    unsigned mx = prev > c ? prev : c;
    key = mx < key ? mx : key;
}
__device__ inline float distf(float4 q, float4 p) {
    return fmaf(-2.f, fmaf(q.z, p.z, fmaf(q.y, p.y, q.x * p.x)), q.w + p.w);
}

// ---------------- prep (blocks 0..63) + weight presplit (blocks 64..2271) ----------------
__global__ __launch_bounds__(256) void prep_presplit(
    const float* __restrict__ pc, float* __restrict__ oxyz, float4* __restrict__ pq,
    const float* __restrict__ W0, const float* __restrict__ W1,
    const float* __restrict__ W2, const float* __restrict__ W3,
    const float* __restrict__ W4, const float* __restrict__ W5,
    unsigned short* __restrict__ wsp) {
    int bx = blockIdx.x, tid = threadIdx.x;
    if (bx < 64) {
        int t = bx * 256 + tid;
        float x = pc[t * 3 + 0], y = pc[t * 3 + 1], z = pc[t * 3 + 2];
        oxyz[t * 3 + 0] = x; oxyz[t * 3 + 1] = y; oxyz[t * 3 + 2] = z;
        pq[t] = make_float4(x, y, z, fmaf(z, z, fmaf(y, y, x * x)));
        return;
    }
    int pb = bx - 64;
    const float* W; int O, C, OP; size_t off; int base;
    if (pb < 1024)      { W = W0; O = 256; C = 1024; OP = 256; off = 0;       base = 0; }
    else if (pb < 1152) { W = W1; O =  64; C =  256; OP = 128; off = 524288;  base = 1024; }
    else if (pb < 1184) { W = W2; O =  32; C =   64; OP = 128; off = 589824;  base = 1152; }
    else if (pb < 1568) { W = W3; O = 512; C =  164; OP = 512; off = 606208;  base = 1184; }
    else if (pb < 2080) { W = W4; O = 256; C =  512; OP = 256; off = 802816;  base = 1568; }
    else                { W = W5; O = 128; C =  256; OP = 128; off = 1064960; base = 2080; }
    unsigned short* dst = wsp + off;
    int t = (pb - base) * 256 + tid;
    int kk = t & 31;
    int o = (t >> 5) % OP;
    int kt = t / (OP * 32);
    int c = kt * 32 + kk;
    float x = (o < O && c < C) ? W[o * C + c] : 0.f;
    unsigned short hb = f2bf(x);
    float hf = __uint_as_float((unsigned)hb << 16);
    unsigned short lb = f2bf(x - hf);
    int s = kk >> 3, pos = kk & 7;
    int sst = s ^ ((o >> 1) & 3);            // pre-swizzle for conflict-free read
    dst[((size_t)(kt * 2) * OP + o) * 32 + sst * 8 + pos] = hb;
    dst[((size_t)(kt * 2 + 1) * OP + o) * 32 + sst * 8 + pos] = lb;
}

// ---------------- GEMM body: BO=64 tile, 4 waves 2x2 (wave 32x32) ----------------
template <int MODE>
__device__ __forceinline__ void gemm_body(
    int nblk, int oy, int b,
    const unsigned short* __restrict__ Wsp, const float* __restrict__ bias,
    const float* __restrict__ X, float* __restrict__ out,
    int O, int C, int OP, int nK,
    const float2* __restrict__ stats,
    const float* __restrict__ h1, const float* __restrict__ h3,
    const float2* __restrict__ stats3,
    float2* __restrict__ partout) {
    const int N = NPTS;
    int tid = threadIdx.x;
    int lane = tid & 63, w = tid >> 6;
    int wm = w >> 1, wn = w & 1;
    int n0 = nblk * 64, o0 = oy * 64;
    int n = n0 + lane;

    __shared__ __align__(16) unsigned char lds[18432];
    __shared__ float ps1[2][64], ps2[2][64];
    unsigned char* WHp = lds;            // [64][64B] linear (swizzled slots)
    unsigned char* WLp = lds + 4096;
    unsigned char* XHp = lds + 8192;     // [64][80B]
    unsigned char* XLp = lds + 13312;

    f32x4 acc[2][2];
#pragma unroll
    for (int i = 0; i < 2; ++i)
#pragma unroll
        for (int j = 0; j < 2; ++j) acc[i][j] = (f32x4){0.f, 0.f, 0.f, 0.f};

    float xcur[8], xnxt[8];
    auto loadx = [&](int kt, float (&dst)[8]) {
#pragma unroll
        for (int i = 0; i < 8; ++i) {
            int c = kt * 32 + w * 8 + i;
            float x = 0.f;
            if (MODE == 0 || MODE == 1) {
                if (c < C) x = X[((size_t)(b * C + c)) * N + n];
            } else {
                if (c < 128)       x = h1[((size_t)(b * 128 + c)) * N + n];
                else if (c < 160)  x = X[((size_t)(b * 32 + (c - 128))) * N + n];
                else if (c < 164)  x = h3[((size_t)(b * 4 + (c - 160))) * N + n];
            }
            dst[i] = x;
        }
    };

    loadx(0, xcur);
    for (int kt = 0; kt < nK; ++kt) {
        int c0 = kt * 32;
#pragma unroll
        for (int comp = 0; comp < 2; ++comp) {
            const unsigned short* gb = Wsp + ((size_t)(kt * 2 + comp) * OP + o0) * 32;
            unsigned char* lb = comp ? WLp : WHp;
            __builtin_amdgcn_global_load_lds(
                (const __attribute__((address_space(1))) u32*)(gb + w * 512 + lane * 8),
                (__attribute__((address_space(3))) u32*)(lb + w * 1024),
                16, 0, 0);
        }
        {
            union { bf16x8 s; unsigned short u[8]; } hh, ll;
#pragma unroll
            for (int i = 0; i < 8; ++i) {
                int c = c0 + w * 8 + i;
                float x = xcur[i];
                if (MODE == 1) {
                    if (c < C) {
                        float2 st = stats[c];
                        x = fmaxf(fmaf(x, st.x, st.y), 0.f);
                    }
                } else if (MODE == 2) {
                    if (c >= 128 && c < 160) {
                        float2 st = stats3[c - 128];
                        x = fmaxf(fmaf(x, st.x, st.y), 0.f);
                    }
                }
                unsigned short hb = f2bf(x);
                float hf = __uint_as_float((unsigned)hb << 16);
                unsigned short lb = f2bf(x - hf);
                hh.u[i] = hb; ll.u[i] = lb;
            }
            *(bf16x8*)(XHp + lane * 80 + w * 16) = hh.s;
            *(bf16x8*)(XLp + lane * 80 + w * 16) = ll.s;
        }
        if (kt + 1 < nK) loadx(kt + 1, xnxt);
        __syncthreads();
        {
            int koff = (lane >> 4) * 16;
            bf16x8 bh[2], bl[2];
#pragma unroll
            for (int ni = 0; ni < 2; ++ni) {
                int rb = wn * 32 + ni * 16 + (lane & 15);
                bh[ni] = *(const bf16x8*)(XHp + rb * 80 + koff);
                bl[ni] = *(const bf16x8*)(XLp + rb * 80 + koff);
            }
#pragma unroll
            for (int mi = 0; mi < 2; ++mi) {
                int ra = wm * 32 + mi * 16 + (lane & 15);
                int sw = koff ^ ((((unsigned)ra >> 1) & 3) * 16);
                bf16x8 ah = *(const bf16x8*)(WHp + ra * 64 + sw);
                bf16x8 al = *(const bf16x8*)(WLp + ra * 64 + sw);
#pragma unroll
                for (int ni = 0; ni < 2; ++ni) {
                    acc[mi][ni] = __builtin_amdgcn_mfma_f32_16x16x32_bf16(ah, bh[ni], acc[mi][ni], 0, 0, 0);
                    acc[mi][ni] = __builtin_amdgcn_mfma_f32_16x16x32_bf16(ah, bl[ni], acc[mi][ni], 0, 0, 0);
                    acc[mi][ni] = __builtin_amdgcn_mfma_f32_16x16x32_bf16(al, bh[ni], acc[mi][ni], 0, 0, 0);
                }
            }
        }
        __syncthreads();
        if (kt + 1 < nK) {
#pragma unroll
            for (int i = 0; i < 8; ++i) xcur[i] = xnxt[i];
        }
    }
    // epilogue
    int col = lane & 15, rq = lane >> 4;
#pragma unroll
    for (int mi = 0; mi < 2; ++mi) {
#pragma unroll
        for (int j = 0; j < 4; ++j) {
            int oloc = wm * 32 + mi * 16 + rq * 4 + j;
            int o = o0 + oloc;
            float s1 = 0.f, s2 = 0.f;
            if (o < O) {
                float bs = bias[o];
                float v0 = acc[mi][0][j] + bs;
                float v1 = acc[mi][1][j] + bs;
                float* po = out + ((size_t)(b * O + o)) * N + n0 + wn * 32 + col;
                po[0] = v0; po[16] = v1;
                s1 = v0 + v1;
                s2 = fmaf(v0, v0, v1 * v1);
            }
#pragma unroll
            for (int mm = 1; mm < 16; mm <<= 1) {
                s1 += __shfl_xor(s1, mm, 64);
                s2 += __shfl_xor(s2, mm, 64);
            }
            if (col == 0) { ps1[wn][oloc] = s1; ps2[wn][oloc] = s2; }
        }
    }
    __syncthreads();
    if (tid < 64) {
        int o = o0 + tid;
        if (o < O)
            partout[(size_t)o * 256 + b * 128 + nblk] =
                make_float2(ps1[0][tid] + ps1[1][tid], ps2[0][tid] + ps2[1][tid]);
    }
}

template <int MODE>
__global__ __launch_bounds__(256, 4) void mfma_gemm(
    const unsigned short* __restrict__ Wsp, const float* __restrict__ bias,
    const float* __restrict__ X, float* __restrict__ out,
    int O, int C, int OP, int nK,
    const float2* __restrict__ stats,
    const float* __restrict__ h1, const float* __restrict__ h3,
    const float2* __restrict__ stats3,
    float2* __restrict__ partout) {
    gemm_body<MODE>(blockIdx.x, blockIdx.y, blockIdx.z, Wsp, bias, X, out, O, C, OP, nK,
                    stats, h1, h3, stats3, partout);
}

// ---------------- KNN body: 2 queries/wave, 2-tile pipelined scan ----------------
__device__ void knn_body(int kb, const float4* __restrict__ pq,
                         const float* __restrict__ ew1, const float* __restrict__ eb1,
                         const float* __restrict__ ew2, const float* __restrict__ eb2,
                         float* __restrict__ h3) {
    int wv = threadIdx.x >> 6;
    int lane = threadIdx.x & 63;
    int sg = kb * 4 + wv;                  // query-pair id, 0..8191
    int b = sg >> 12;
    int iloc = (sg & 4095) << 1;
    const float4* pqb = pq + (size_t)b * NPTS;
    float4 Q0 = pqb[iloc + 0], Q1 = pqb[iloc + 1];

    float4 p = pqb[lane];
    unsigned k0 = bitonic64u(pack32(distf(Q0, p), lane), lane);
    unsigned k1 = bitonic64u(pack32(distf(Q1, p), lane), lane);
    unsigned tk0 = (unsigned)__builtin_amdgcn_readlane((int)k0, 15);
    unsigned tk1 = (unsigned)__builtin_amdgcn_readlane((int)k1, 15);

    float4 A = pqb[64 + lane];
    float4 B = pqb[128 + lane];
    for (int it = 1; it + 1 < 128; it += 2) {
        int tbA = it * 64, tbB = tbA + 64;
        int t3 = (it + 3 < 128) ? it + 3 : 0;
        float4 Cx = pqb[(it + 2) * 64 + lane];
        float4 Dx = pqb[t3 * 64 + lane];
        unsigned cA0 = pack32(distf(Q0, A), tbA + lane);
        unsigned cA1 = pack32(distf(Q1, A), tbA + lane);
        unsigned cB0 = pack32(distf(Q0, B), tbB + lane);
        unsigned cB1 = pack32(distf(Q1, B), tbB + lane);
        unsigned long long mA0 = __ballot(cA0 < tk0), mB0 = __ballot(cB0 < tk0);
        unsigned long long mA1 = __ballot(cA1 < tk1), mB1 = __ballot(cB1 < tk1);
        if (mA0 | mA1 | mB0 | mB1) {
            while (mA0) {
                int L = __ffsll((long long)mA0) - 1; mA0 &= mA0 - 1;
                ins16(k0, (unsigned)__builtin_amdgcn_readlane((int)cA0, L), lane);
            }
            while (mB0) {
                int L = __ffsll((long long)mB0) - 1; mB0 &= mB0 - 1;
                ins16(k0, (unsigned)__builtin_amdgcn_readlane((int)cB0, L), lane);
            }
            while (mA1) {
                int L = __ffsll((long long)mA1) - 1; mA1 &= mA1 - 1;
                ins16(k1, (unsigned)__builtin_amdgcn_readlane((int)cA1, L), lane);
            }
            while (mB1) {
                int L = __ffsll((long long)mB1) - 1; mB1 &= mB1 - 1;
                ins16(k1, (unsigned)__builtin_amdgcn_readlane((int)cB1, L), lane);
            }
            tk0 = (unsigned)__builtin_amdgcn_readlane((int)k0, 15);
            tk1 = (unsigned)__builtin_amdgcn_readlane((int)k1, 15);
        }
        A = Cx; B = Dx;
    }
    {
        int tbA = 127 * 64;
        unsigned cA0 = pack32(distf(Q0, A), tbA + lane);
        unsigned cA1 = pack32(distf(Q1, A), tbA + lane);
        unsigned long long mA0 = __ballot(cA0 < tk0);
        unsigned long long mA1 = __ballot(cA1 < tk1);
        while (mA0) {
            int L = __ffsll((long long)mA0) - 1; mA0 &= mA0 - 1;
            ins16(k0, (unsigned)__builtin_amdgcn_readlane((int)cA0, L), lane);
        }
        while (mA1) {
            int L = __ffsll((long long)mA1) - 1; mA1 &= mA1 - 1;
            ins16(k1, (unsigned)__builtin_amdgcn_readlane((int)cA1, L), lane);
        }
    }

    int g = lane >> 4, r = lane & 15;
    unsigned j0 = ((unsigned)__shfl((int)k0, r, 64)) & 8191u;
    unsigned j1 = ((unsigned)__shfl((int)k1, r, 64)) & 8191u;
    unsigned nj = ((g & 1) == 0) ? j0 : j1;

    float4 nb = pqb[nj];
    float sx = nb.x, sy = nb.y, sz = nb.z;
#pragma unroll
    for (int m = 1; m < 16; m <<= 1) {
        sx += __shfl_xor(sx, m, 64);
        sy += __shfl_xor(sy, m, 64);
        sz += __shfl_xor(sz, m, 64);
    }
    const float i16 = 1.f / 16.f;
    float cx = nb.x - sx * i16, cy = nb.y - sy * i16, cz = nb.z - sz * i16;
    float xx = cx * cx, xy = cx * cy, xz = cx * cz, yy = cy * cy, yz = cy * cz, zz = cz * cz;
#pragma unroll
    for (int m = 1; m < 16; m <<= 1) {
        xx += __shfl_xor(xx, m, 64); xy += __shfl_xor(xy, m, 64); xz += __shfl_xor(xz, m, 64);
        yy += __shfl_xor(yy, m, 64); yz += __shfl_xor(yz, m, 64); zz += __shfl_xor(zz, m, 64);
    }
    float a11 = xx * i16, a12 = xy * i16, a13 = xz * i16,
          a22 = yy * i16, a23 = yz * i16, a33 = zz * i16;
    float q = (a11 + a22 + a33) * (1.f / 3.f);
    float p1 = a12 * a12 + a13 * a13 + a23 * a23;
    float b11 = a11 - q, b22 = a22 - q, b33 = a33 - q;
    float p2 = b11 * b11 + b22 * b22 + b33 * b33 + 2.f * p1;
    float pr = sqrtf(p2 * (1.f / 6.f));
    float ipv = (p2 > 1e-32f) ? (1.f / pr) : 0.f;
    float detB = b11 * (b22 * b33 - a23 * a23) - a12 * (a12 * b33 - a23 * a13) +
                 a13 * (a12 * a23 - b22 * a13);
    float r3 = 0.5f * detB * ipv * ipv * ipv;
    r3 = fminf(1.f, fmaxf(-1.f, r3));
    float phi = acosf(r3) * (1.f / 3.f);
    float e1 = q + 2.f * pr * cosf(phi);
    float e3 = q + 2.f * pr * cosf(phi + 2.0943951023931953f);
    float e2 = 3.f * q - e1 - e3;
    float ev0 = e3, ev1 = e2, ev2 = e1;
    float h[4], o[4];
#pragma unroll
    for (int kk = 0; kk < 4; ++kk)
        h[kk] = fmaxf(eb1[kk] + ev0 * ew1[kk] + ev1 * ew1[4 + kk] + ev2 * ew1[8 + kk], 0.f);
#pragma unroll
    for (int kk = 0; kk < 4; ++kk)
        o[kk] = eb2[kk] + h[0] * ew2[kk] + h[1] * ew2[4 + kk] + h[2] * ew2[8 + kk] +
                h[3] * ew2[12 + kk];
    int ipt = iloc + (g & 1);
    if (r == 0 && g < 2) {
#pragma unroll
        for (int kk = 0; kk < 4; ++kk) h3[(b * 4 + kk) * NPTS + ipt] = o[kk];
    }
}

// ---------------- fused: DG1 GEMM (blocks 0..1023) + KNN (blocks 1024..3071) ----------------
// Matched resource shapes: ~19.5KB LDS, VGPR<=64 -> both paths keep 8 blocks/CU.
__global__ __launch_bounds__(256, 4) void dg1_knn(
    const unsigned short* __restrict__ Wsp, const float* __restrict__ bias,
    const float* __restrict__ X, float* __restrict__ out, float2* __restrict__ partout,
    const float4* __restrict__ pq,
    const float* __restrict__ ew1, const float* __restrict__ eb1,
    const float* __restrict__ ew2, const float* __restrict__ eb2,
    float* __restrict__ h3) {
    if (blockIdx.x < 1024) {
        int bid = blockIdx.x;
        gemm_body<0>(bid & 127, (bid >> 7) & 3, bid >> 9, Wsp, bias, X, out,
                     256, 1024, 256, 32, nullptr, nullptr, nullptr, nullptr, partout);
    } else {
        knn_body(blockIdx.x - 1024, pq, ew1, eb1, ew2, eb2, h3);
    }
}

// ---------------- finalize stats from partials: one block per channel ----------------
__global__ __launch_bounds__(256) void finalize_kernel(const float2* __restrict__ part,
                                                       const float* __restrict__ g,
                                                       const float* __restrict__ be,
                                                       float2* __restrict__ st) {
    int c = blockIdx.x;
    int tid = threadIdx.x;
    __shared__ float r1[256], r2[256];
    float2 v = part[(size_t)c * 256 + tid];
    r1[tid] = v.x; r2[tid] = v.y;
    __syncthreads();
    for (int off = 128; off > 0; off >>= 1) {
        if (tid < off) { r1[tid] += r1[tid + off]; r2[tid] += r2[tid + off]; }
        __syncthreads();
    }
    if (tid == 0) {
        const float inv = 1.f / (BATCH * NPTS);
        float m = r1[0] * inv;
        float var = r2[0] * inv - m * m;
        float sc = g[c] * rsqrtf(var + 1e-5f);
        st[c] = make_float2(sc, be[c] - m * sc);
    }
}

// ---------------- C3 stats (from partials) + bn_relu into d_out ----------------
__global__ __launch_bounds__(256) void stats_final_kernel(
    const float2* __restrict__ part, const float* __restrict__ g,
    const float* __restrict__ be, const float* __restrict__ X,
    float* __restrict__ outz) {
    const int N = NPTS;
    const int C = 128;
    int c = blockIdx.x;
    int tid = threadIdx.x;
    __shared__ float r1[256], r2[256];
    __shared__ float2 stv;
    float2 v = part[(size_t)c * 256 + tid];
    r1[tid] = v.x; r2[tid] = v.y;
    __syncthreads();
    for (int off = 128; off > 0; off >>= 1) {
        if (tid < off) { r1[tid] += r1[tid + off]; r2[tid] += r2[tid + off]; }
        __syncthreads();
    }
    if (tid == 0) {
        const float inv = 1.f / (BATCH * NPTS);
        float m = r1[0] * inv;
        float var = r2[0] * inv - m * m;
        float sc = g[c] * rsqrtf(var + 1e-5f);
        stv = make_float2(sc, be[c] - m * sc);
    }
    __syncthreads();
    float2 s = stv;
    for (int b = 0; b < BATCH; ++b) {
        const float* p = X + (size_t)(b * C + c) * N;
        float* q = outz + (size_t)(b * C + c) * N;
        for (int nn = tid * 4; nn < N; nn += 1024) {
            float4 v4 = *(const float4*)(p + nn);
            v4.x = fmaxf(fmaf(v4.x, s.x, s.y), 0.f);
            v4.y = fmaxf(fmaf(v4.y, s.x, s.y), 0.f);
            v4.z = fmaxf(fmaf(v4.z, s.x, s.y), 0.f);
            v4.w = fmaxf(fmaf(v4.w, s.x, s.y), 0.f);
            *(float4*)(q + nn) = v4;
        }
    }
}

// ---------------- launch ----------------
extern "C" void kernel_launch(void* const* d_in, const int* in_sizes, int n_in,
                              void* d_out, int out_size, void* d_ws, size_t ws_size,
                              hipStream_t stream) {
    const float* pc    = (const float*)d_in[0];
    const float* h1    = (const float*)d_in[1];
    const float* h2    = (const float*)d_in[2];
    const float* DG_w1 = (const float*)d_in[4];
    const float* DG_b1 = (const float*)d_in[5];
    const float* DG_g1 = (const float*)d_in[6];
    const float* DG_be1= (const float*)d_in[7];
    const float* DG_w2 = (const float*)d_in[8];
    const float* DG_b2 = (const float*)d_in[9];
    const float* DG_g2 = (const float*)d_in[10];
    const float* DG_be2= (const float*)d_in[11];
    const float* DG_w3 = (const float*)d_in[12];
    const float* DG_b3 = (const float*)d_in[13];
    const float* DG_g3 = (const float*)d_in[14];
    const float* DG_be3= (const float*)d_in[15];
    const float* ED_w1 = (const float*)d_in[16];
    const float* ED_b1 = (const float*)d_in[17];
    const float* ED_w2 = (const float*)d_in[18];
    const float* ED_b2 = (const float*)d_in[19];
    const float* C_w1  = (const float*)d_in[20];
    const float* C_b1  = (const float*)d_in[21];
    const float* C_g1  = (const float*)d_in[22];
    const float* C_be1 = (const float*)d_in[23];
    const float* C_w2  = (const float*)d_in[24];
    const float* C_b2  = (const float*)d_in[25];
    const float* C_g2  = (const float*)d_in[26];
    const float* C_be2 = (const float*)d_in[27];
    const float* C_w3  = (const float*)d_in[28];
    const float* C_b3  = (const float*)d_in[29];
    const float* C_g3  = (const float*)d_in[30];
    const float* C_be3 = (const float*)d_in[31];

    float* ws = (float*)d_ws;
    float* A  = ws;                       // DG1-out then C1-out
    float* Bb = ws + (8l << 20);          // DG2-out then C2-out
    float* Cc = ws + (12l << 20);         // DG3-out then C3-out
    float* H3 = ws + (14l << 20);         // 65536 floats
    float4* PQ = (float4*)(H3 + 65536);   // 16384 float4
    float2* ST = (float2*)(H3 + 131072);  // finalized stats
    unsigned short* WSP = (unsigned short*)(H3 + 131072 + 2560);

    // partial-stats buffers in liveness-safe slack:
    float2* P_DG1 = (float2*)(Bb + (1l << 20));                       // 65536 f2
    float2* P_DG2 = (float2*)(Bb + (1l << 20) + 131072);              // 16384 f2
    float2* P_DG3 = (float2*)(Bb + (1l << 20) + 131072 + 32768);      //  8192 f2
    float2* P_C1  = (float2*)(Cc + (1l << 20));                       // 131072 f2
    float2* TAIL  = (float2*)(WSP + 1130496);
    float2* P_C2  = TAIL;                                             // 65536 f2
    float2* P_C3  = TAIL + 65536;                                     // 32768 f2

    const size_t W1SP = 0;
    const size_t W2SP = 524288;
    const size_t W3SP = 589824;
    const size_t C1SP = 606208;
    const size_t C2SP = 802816;
    const size_t C3SP = 1064960;

    float* outxyz = (float*)d_out;
    float* outz   = (float*)d_out + BATCH * NPTS * 3;

    prep_presplit<<<2272, 256, 0, stream>>>(pc, outxyz, PQ,
                                            DG_w1, DG_w2, DG_w3, C_w1, C_w2, C_w3, WSP);

    // DG1 GEMM + KNN fused (matched resource shapes, disjoint block ranges)
    dg1_knn<<<3072, 256, 0, stream>>>(WSP + W1SP, DG_b1, h2, A, P_DG1,
                                      PQ, ED_w1, ED_b1, ED_w2, ED_b2, H3);
    finalize_kernel<<<256, 256, 0, stream>>>(P_DG1, DG_g1, DG_be1, ST + 0);
    mfma_gemm<1><<<dim3(128, 1, 2), 256, 0, stream>>>(WSP + W2SP, DG_b2, A, Bb, 64, 256, 128, 8,
                                                      ST + 0, nullptr, nullptr, nullptr, P_DG2);
    finalize_kernel<<<64, 256, 0, stream>>>(P_DG2, DG_g2, DG_be2, ST + 256);
    mfma_gemm<1><<<dim3(128, 1, 2), 256, 0, stream>>>(WSP + W3SP, DG_b3, Bb, Cc, 32, 64, 128, 2,
                                                      ST + 256, nullptr, nullptr, nullptr, P_DG3);
    finalize_kernel<<<32, 256, 0, stream>>>(P_DG3, DG_g3, DG_be3, ST + 320);

    // C stack
    mfma_gemm<2><<<dim3(128, 8, 2), 256, 0, stream>>>(WSP + C1SP, C_b1, Cc, A, 512, 164, 512, 6,
                                                      nullptr, h1, H3, ST + 320, P_C1);
    finalize_kernel<<<512, 256, 0, stream>>>(P_C1, C_g1, C_be1, ST + 352);
    mfma_gemm<1><<<dim3(128, 4, 2), 256, 0, stream>>>(WSP + C2SP, C_b2, A, Bb, 256, 512, 256, 16,
                                                      ST + 352, nullptr, nullptr, nullptr, P_C2);
    finalize_kernel<<<256, 256, 0, stream>>>(P_C2, C_g2, C_be2, ST + 864);
    mfma_gemm<1><<<dim3(128, 2, 2), 256, 0, stream>>>(WSP + C3SP, C_b3, Bb, Cc, 128, 256, 128, 8,
                                                      ST + 864, nullptr, nullptr, nullptr, P_C3);

    // C3 stats (from partials) + bn_relu, writes final output
    stats_final_kernel<<<128, 256, 0, stream>>>(P_C3, C_g3, C_be3, Cc, outz);
}